// Round 14
// baseline (2540.472 us; speedup 1.0000x reference)
//
#include <hip/hip_runtime.h>

typedef unsigned int u32;
typedef unsigned long long u64;
typedef float f32x2 __attribute__((ext_vector_type(2)));

#define NPB 8192
#define BCL 4
#define MS 2048
#define KN 64
#define OFF_POS   (BCL * MS * 128)            // element offsets into d_out (f32)
#define OFF_BATCH (OFF_POS + BCL * MS * 3)

__device__ inline u64 umax64(u64 a, u64 b) { return a < b ? b : a; }
__device__ inline u32 umax32(u32 a, u32 b) { return a < b ? b : a; }

// packed f32 ops: IEEE-identical per half to v_add_f32 / v_mul_f32 -> bit-exact
__device__ inline f32x2 pk_add(f32x2 a, f32x2 b) {
  f32x2 d;
  asm("v_pk_add_f32 %0, %1, %2" : "=v"(d) : "v"(a), "v"(b));
  return d;
}
__device__ inline f32x2 pk_mul(f32x2 a, f32x2 b) {
  f32x2 d;
  asm("v_pk_mul_f32 %0, %1, %2" : "=v"(d) : "v"(a), "v"(b));
  return d;
}

// wave64 max via DPP (VALU forwarding, no LDS round-trips).
__device__ inline u32 wave_max_u32(u32 v) {
  v = umax32(v, (u32)__builtin_amdgcn_update_dpp(0, (int)v, 0x111, 0xf, 0xf, false));
  v = umax32(v, (u32)__builtin_amdgcn_update_dpp(0, (int)v, 0x112, 0xf, 0xf, false));
  v = umax32(v, (u32)__builtin_amdgcn_update_dpp(0, (int)v, 0x114, 0xf, 0xf, false));
  v = umax32(v, (u32)__builtin_amdgcn_update_dpp(0, (int)v, 0x118, 0xf, 0xf, false));
  v = umax32(v, (u32)__builtin_amdgcn_update_dpp(0, (int)v, 0x142, 0xa, 0xf, false));
  v = umax32(v, (u32)__builtin_amdgcn_update_dpp(0, (int)v, 0x143, 0xc, 0xf, false));
  return (u32)__builtin_amdgcn_readlane((int)v, 63);
}
// two-phase DPP reduce == lexicographic u64 max over the wave (tie -> min idx)
__device__ inline u64 wave_max_key(u64 lkey) {
  u32 hi = (u32)(lkey >> 32), lo32v = (u32)lkey;
  u32 m = wave_max_u32(hi);
  u32 c = wave_max_u32(hi == m ? lo32v : 0u);
  return ((u64)m << 32) | c;
}

__device__ inline u32 part1by2(u32 x) {   // spread 10 bits -> every 3rd bit
  x &= 0x3ffu;
  x = (x | (x << 16)) & 0x030000FFu;
  x = (x | (x << 8))  & 0x0300F00Fu;
  x = (x | (x << 4))  & 0x030C30C3u;
  x = (x | (x << 2))  & 0x09249249u;
  return x;
}

// ===========================================================================
// Fused kernel. grid = 4 + 8192 blocks x 1024 thr, 64 KB dynamic LDS.
// Role via global ticket: first 4 arrivals run FPS (R11-proven body, 1488us)
// for cloud=role, publishing each winner as flag[c]=win+1 (relaxed atomic;
// the atomic VALUE is the payload -> no fence needed). Other blocks handle
// center c=role-4: spin on flag[c], then radius-ball + sort (proven nbr) and
// f32 MLP (proven arithmetic, k-sequential order -> bit-exact) fused.
// No dispatch-order assumption: whichever blocks run first take fps tickets.
// ===========================================================================
__global__ __launch_bounds__(1024) void fused_kernel(
    const float* __restrict__ pos, const float* __restrict__ x,
    const float* __restrict__ W1, const float* __restrict__ b1,
    const float* __restrict__ W2, const float* __restrict__ b2,
    const float* __restrict__ W3, const float* __restrict__ b3,
    u32* __restrict__ flag, int* __restrict__ ticket,
    float* __restrict__ out) {
  extern __shared__ u64 smem[];   // 64 KB, multi-purpose
  int t = threadIdx.x;

  // ---- role claim (first-arrival basis; no blockIdx-order assumption) ----
  if (t == 0) *(int*)smem = atomicAdd(ticket, 1);
  __syncthreads();
  int role = *(int*)smem;
  __syncthreads();

  if (role < BCL) {
    // =====================================================================
    // FPS for cloud b = role. R11 body verbatim + flag publication.
    // =====================================================================
    int b = role, lane = t & 63;
    const float* pb = pos + (size_t)b * NPB * 3;

    for (int i = t; i < NPB; i += 1024) {
      float xx = pb[i * 3], yy = pb[i * 3 + 1], zz = pb[i * 3 + 2];
      u32 xi = (u32)fminf(fmaxf(xx * 1024.0f, 0.0f), 1023.0f);
      u32 yi = (u32)fminf(fmaxf(yy * 1024.0f, 0.0f), 1023.0f);
      u32 zi = (u32)fminf(fmaxf(zz * 1024.0f, 0.0f), 1023.0f);
      u32 m = (part1by2(zi) << 2) | (part1by2(yi) << 1) | part1by2(xi);
      smem[i] = ((u64)m << 13) | (u32)i;
    }
    for (int k = 2; k <= NPB; k <<= 1) {
      for (int j = k >> 1; j > 0; j >>= 1) {
        __syncthreads();
        for (int i = t; i < NPB; i += 1024) {
          int ix = i ^ j;
          if (ix > i) {
            u64 a = smem[i], c = smem[ix];
            bool up = ((i & k) == 0);
            if ((a > c) == up) { smem[i] = c; smem[ix] = a; }
          }
        }
      }
    }
    __syncthreads();
    int oi[8];
    #pragma unroll
    for (int i = 0; i < 8; ++i) oi[i] = (int)(smem[8 * t + i] & 0x1FFFu);
    __syncthreads();

    u64* slot = smem;                // [3] triple-buffered atomicMax slots
    int* s_samp = (int*)(smem + 8);  // 2048 ints

    f32x2 px[4], py[4], pz[4], mind[4];
    u32 lo[8];
    float bxl = 1e30f, bxh = -1e30f, byl = 1e30f, byh = -1e30f, bzl = 1e30f, bzh = -1e30f;
    #pragma unroll
    for (int j = 0; j < 4; ++j) {
      int iA = oi[2 * j], iB = oi[2 * j + 1];
      float xA = pb[iA * 3], yA = pb[iA * 3 + 1], zA = pb[iA * 3 + 2];
      float xB = pb[iB * 3], yB = pb[iB * 3 + 1], zB = pb[iB * 3 + 2];
      px[j] = f32x2{xA, xB}; py[j] = f32x2{yA, yB}; pz[j] = f32x2{zA, zB};
      lo[2 * j] = ~(u32)iA; lo[2 * j + 1] = ~(u32)iB;
      bxl = fminf(bxl, fminf(xA, xB)); bxh = fmaxf(bxh, fmaxf(xA, xB));
      byl = fminf(byl, fminf(yA, yB)); byh = fmaxf(byh, fmaxf(yA, yB));
      bzl = fminf(bzl, fminf(zA, zB)); bzh = fmaxf(bzh, fmaxf(zA, zB));
    }
    u64 lkey = 0, wkey;
    {
      float cx = pb[0], cy = pb[1], cz = pb[2];
      f32x2 mcx = f32x2{-cx, -cx}, mcy = f32x2{-cy, -cy}, mcz = f32x2{-cz, -cz};
      #pragma unroll
      for (int j = 0; j < 4; ++j) {
        f32x2 dx = pk_add(px[j], mcx), dy = pk_add(py[j], mcy), dz = pk_add(pz[j], mcz);
        mind[j] = pk_add(pk_add(pk_mul(dx, dx), pk_mul(dy, dy)), pk_mul(dz, dz));
        u64 kA = ((u64)__float_as_uint(mind[j].x) << 32) | lo[2 * j];
        u64 kB = ((u64)__float_as_uint(mind[j].y) << 32) | lo[2 * j + 1];
        lkey = umax64(lkey, umax64(kA, kB));
      }
      wkey = wave_max_key(lkey);
    }
    if (t < 3) slot[t] = 0;
    if (t == 0) {
      s_samp[0] = 0;
      __hip_atomic_store(&flag[b * MS], 1u, __ATOMIC_RELAXED,
                         __HIP_MEMORY_SCOPE_AGENT);   // center 0: win=0
    }
    __syncthreads();

    int cur = 0, nxt = 1;
    for (int it = 1; it < MS; ++it) {
      if (lane == 0) atomicMax((u64*)&slot[cur], wkey);
      if (t == 0) slot[nxt] = 0;
      __syncthreads();
      u64 g = slot[cur];
      int win = (int)(~(u32)g) & (NPB - 1);
      if (t == 0) {
        s_samp[it] = win;
        __hip_atomic_store(&flag[b * MS + it], (u32)win + 1u, __ATOMIC_RELAXED,
                           __HIP_MEMORY_SCOPE_AGENT);
      }
      float ncx = pb[win * 3], ncy = pb[win * 3 + 1], ncz = pb[win * 3 + 2];
      float lmax = __uint_as_float((u32)(lkey >> 32));
      float ax = fmaxf(fmaxf(__fsub_rn(bxl, ncx), __fsub_rn(ncx, bxh)), 0.0f);
      float ay = fmaxf(fmaxf(__fsub_rn(byl, ncy), __fsub_rn(ncy, byh)), 0.0f);
      float az = fmaxf(fmaxf(__fsub_rn(bzl, ncz), __fsub_rn(ncz, bzh)), 0.0f);
      float lb2 = (ax * ax + ay * ay + az * az) * 0.9999961853f;  // *(1-2^-18)
      bool upd = (lb2 <= lmax);
      if (__ballot(upd)) {
        if (upd) {
          f32x2 mcx = f32x2{-ncx, -ncx}, mcy = f32x2{-ncy, -ncy}, mcz = f32x2{-ncz, -ncz};
          u64 acc = 0;
          #pragma unroll
          for (int j = 0; j < 4; ++j) {
            f32x2 dx = pk_add(px[j], mcx), dy = pk_add(py[j], mcy), dz = pk_add(pz[j], mcz);
            f32x2 d2 = pk_add(pk_add(pk_mul(dx, dx), pk_mul(dy, dy)), pk_mul(dz, dz));
            mind[j].x = fminf(mind[j].x, d2.x);
            mind[j].y = fminf(mind[j].y, d2.y);
            u64 kA = ((u64)__float_as_uint(mind[j].x) << 32) | lo[2 * j];
            u64 kB = ((u64)__float_as_uint(mind[j].y) << 32) | lo[2 * j + 1];
            acc = umax64(acc, umax64(kA, kB));
          }
          lkey = acc;
        }
        wkey = wave_max_key(lkey);
      }
      cur = nxt;
      nxt = nxt + 1 == 3 ? 0 : nxt + 1;
    }
    __syncthreads();
    float* pos_out = out + OFF_POS + (size_t)b * MS * 3;
    float* batch_out = out + OFF_BATCH + (size_t)b * MS;
    for (int m = t; m < MS; m += 1024) {
      int s = s_samp[m];
      pos_out[m * 3] = pb[s * 3];
      pos_out[m * 3 + 1] = pb[s * 3 + 1];
      pos_out[m * 3 + 2] = pb[s * 3 + 2];
      batch_out[m] = (float)b;
    }
    return;
  }

  // =======================================================================
  // Consumer: center c = role - 4. Spin on flag[c], then nbr + MLP.
  // =======================================================================
  int c = role - BCL;
  int b = c >> 11;
  const float* pb = pos + (size_t)b * NPB * 3;

  // LDS carve (<= 60.9 KB of the 64 KB dynamic buffer)
  u64* cand = smem;                              // 512 u64   (4096 B)
  float* s_feat = (float*)(smem + 512);          // [64][68]  (17408 B)
  float* s_h = s_feat + 64 * 68;                 // [64][68]  (17408 B)
  float* s_w = s_h + 64 * 68;                    // [68][64]  (17408 B)
  float* s_red = s_w + 68 * 64;                  // [16][64]  (4096 B)
  float* s_mask = s_red + 16 * 64;               // 64        (256 B)
  int* s_nbr = (int*)(s_mask + 64);              // 64        (256 B)
  int* s_int = s_nbr + 64;                       // cnt, win

  if (t == 0) {
    u32 v;
    while ((v = __hip_atomic_load(&flag[c], __ATOMIC_RELAXED,
                                  __HIP_MEMORY_SCOPE_AGENT)) == 0u)
      __builtin_amdgcn_s_sleep(32);
    s_int[1] = (int)v - 1;        // winner index for this center
    s_int[0] = 0;                 // cnt
  }
  __syncthreads();
  int s = s_int[1] & (NPB - 1);
  float cx = pb[s * 3], cy = pb[s * 3 + 1], cz = pb[s * 3 + 2];

  // ---- radius ball (proven semantics: (d2<<32)|j keys, cap 512) ----
  const float R2CUT = (float)(0.2 * 0.2);   // 0x3D23D70A
  for (int j = t; j < NPB; j += 1024) {
    float dx = __fsub_rn(pb[j * 3], cx);
    float dy = __fsub_rn(pb[j * 3 + 1], cy);
    float dz = __fsub_rn(pb[j * 3 + 2], cz);
    float d2 = __fadd_rn(__fadd_rn(__fmul_rn(dx, dx), __fmul_rn(dy, dy)), __fmul_rn(dz, dz));
    if (d2 <= R2CUT) {
      int sl = atomicAdd(&s_int[0], 1);
      if (sl < 512) cand[sl] = ((u64)__float_as_uint(d2) << 32) | (u32)j;
    }
  }
  __syncthreads();
  int n = s_int[0]; if (n > 512) n = 512;
  for (int i = t; i < 512; i += 1024) if (i >= n) cand[i] = ~0ull;
  __syncthreads();
  for (int k = 2; k <= 512; k <<= 1) {
    for (int j = k >> 1; j > 0; j >>= 1) {
      for (int i = t; i < 512; i += 1024) {
        int ix = i ^ j;
        if (ix > i) {
          u64 a = cand[i], bb = cand[ix];
          bool up = ((i & k) == 0);
          if ((a > bb) == up) { cand[i] = bb; cand[ix] = a; }
        }
      }
      __syncthreads();
    }
  }
  // ---- neighbor list + mask + posdiff ----
  if (t < KN) {
    int j = (t < n) ? (int)(cand[t] & 0xffffffffu) : -1;
    s_nbr[t] = j;
    bool valid = (j >= 0 && j < NPB);
    s_mask[t] = valid ? 0.0f : -__builtin_inff();
    size_t jj = valid ? (size_t)j : (size_t)s;
    for (int d = 0; d < 3; ++d) {
      float pj = pos[((size_t)b * NPB + jj) * 3 + d];
      float pc = pos[((size_t)b * NPB + s) * 3 + d];
      s_feat[t * 68 + 64 + d] = __fsub_rn(pj, pc);
    }
  }
  __syncthreads();
  // ---- gather x: thread (r = t>>4, q = t&15) loads one float4 ----
  {
    int r = t >> 4, q = t & 15;
    int j = s_nbr[r];
    bool valid = (j >= 0 && j < NPB);
    size_t jj = valid ? (size_t)j : 0;
    float4 v = *(const float4*)(x + ((size_t)b * NPB + jj) * 64 + q * 4);
    s_feat[r * 68 + q * 4 + 0] = valid ? v.x : 0.0f;
    s_feat[r * 68 + q * 4 + 1] = valid ? v.y : 0.0f;
    s_feat[r * 68 + q * 4 + 2] = valid ? v.z : 0.0f;
    s_feat[r * 68 + q * 4 + 3] = valid ? v.w : 0.0f;
  }
  // ---- stage W1 [67][64] ----
  for (int idx = t; idx < 67 * 64; idx += 1024)
    s_w[(idx >> 6) * 64 + (idx & 63)] = W1[idx];
  __syncthreads();

  // ---- layer 1: thread (r = t>>4, n0 = (t&15)*4), k-sequential (bit-exact) ----
  {
    int r = t >> 4, n0 = (t & 15) * 4;
    float acc[4];
    for (int j = 0; j < 4; ++j) acc[j] = b1[n0 + j];
    for (int k = 0; k < 67; ++k) {
      float f = s_feat[r * 68 + k];
      for (int j = 0; j < 4; ++j) acc[j] += f * s_w[k * 64 + n0 + j];
    }
    __syncthreads();               // all W1/s_feat reads done
    for (int j = 0; j < 4; ++j) s_h[r * 68 + n0 + j] = fmaxf(acc[j], 0.0f);
  }
  // ---- stage W2 [64][64] ----
  for (int idx = t; idx < 64 * 64; idx += 1024)
    s_w[(idx >> 6) * 64 + (idx & 63)] = W2[idx];
  __syncthreads();

  // ---- layer 2 (h2 overwrites s_feat cols 0-63) ----
  {
    int r = t >> 4, n0 = (t & 15) * 4;
    float acc[4];
    for (int j = 0; j < 4; ++j) acc[j] = b2[n0 + j];
    for (int k = 0; k < 64; ++k) {
      float f = s_h[r * 68 + k];
      for (int j = 0; j < 4; ++j) acc[j] += f * s_w[k * 64 + n0 + j];
    }
    __syncthreads();               // all W2/s_h reads done
    for (int j = 0; j < 4; ++j) s_feat[r * 68 + n0 + j] = fmaxf(acc[j], 0.0f);
  }
  __syncthreads();

  // ---- layer 3 in two 64-col halves + fused masked max-pool ----
  for (int h = 0; h < 2; ++h) {
    for (int idx = t; idx < 64 * 64; idx += 1024)
      s_w[(idx >> 6) * 64 + (idx & 63)] = W3[(size_t)(idx >> 6) * 128 + h * 64 + (idx & 63)];
    __syncthreads();
    int nn = t & 63, rg = t >> 6;   // 16 row-groups of 4 rows
    float acc[4];
    float bias = b3[h * 64 + nn];
    for (int rr = 0; rr < 4; ++rr) acc[rr] = bias;
    for (int k = 0; k < 64; ++k) {
      float w = s_w[k * 64 + nn];
      for (int rr = 0; rr < 4; ++rr) acc[rr] += s_feat[(rg * 4 + rr) * 68 + k] * w;
    }
    float m = -__builtin_inff();
    for (int rr = 0; rr < 4; ++rr)
      m = fmaxf(m, fmaxf(acc[rr], 0.0f) + s_mask[rg * 4 + rr]);
    s_red[rg * 64 + nn] = m;
    __syncthreads();
    if (t < 64) {
      float mm = -__builtin_inff();
      for (int g2 = 0; g2 < 16; ++g2) mm = fmaxf(mm, s_red[g2 * 64 + t]);
      out[(size_t)c * 128 + h * 64 + t] = mm;
    }
    __syncthreads();               // protect s_w restage for h=1
  }
}

// ---------------------------------------------------------------------------
extern "C" void kernel_launch(void* const* d_in, const int* in_sizes, int n_in,
                              void* d_out, int out_size, void* d_ws, size_t ws_size,
                              hipStream_t stream) {
  const float* x   = (const float*)d_in[0];
  const float* pos = (const float*)d_in[1];
  // d_in[2] = batch (int32), unused
  const float* W1 = (const float*)d_in[3];
  const float* b1 = (const float*)d_in[4];
  const float* W2 = (const float*)d_in[5];
  const float* b2 = (const float*)d_in[6];
  const float* W3 = (const float*)d_in[7];
  const float* b3 = (const float*)d_in[8];

  float* out = (float*)d_out;
  u32* flag = (u32*)d_ws;               // [8192] 0 = not ready, else win+1
  int* ticket = (int*)d_ws + BCL * MS;  // [1]

  hipMemsetAsync(d_ws, 0, (BCL * MS + 1) * sizeof(u32), stream);
  fused_kernel<<<BCL + BCL * MS, 1024, NPB * sizeof(u64), stream>>>(
      pos, x, W1, b1, W2, b2, W3, b3, flag, ticket, out);
}

// Round 15
// 2519.615 us; speedup vs baseline: 1.0083x; 1.0083x over previous
//
#include <hip/hip_runtime.h>

typedef unsigned int u32;
typedef unsigned long long u64;
typedef float f32x2 __attribute__((ext_vector_type(2)));

#define NPB 8192
#define BCL 4
#define MS 2048
#define KN 64
#define OFF_POS   (BCL * MS * 128)            // element offsets into d_out (f32)
#define OFF_BATCH (OFF_POS + BCL * MS * 3)

__device__ inline u64 umax64(u64 a, u64 b) { return a < b ? b : a; }
__device__ inline u32 umax32(u32 a, u32 b) { return a < b ? b : a; }

// packed f32 ops: IEEE-identical per half to v_add_f32 / v_mul_f32 -> bit-exact
__device__ inline f32x2 pk_add(f32x2 a, f32x2 b) {
  f32x2 d;
  asm("v_pk_add_f32 %0, %1, %2" : "=v"(d) : "v"(a), "v"(b));
  return d;
}
__device__ inline f32x2 pk_mul(f32x2 a, f32x2 b) {
  f32x2 d;
  asm("v_pk_mul_f32 %0, %1, %2" : "=v"(d) : "v"(a), "v"(b));
  return d;
}

// wave64 max via DPP (VALU forwarding, no LDS round-trips).
__device__ inline u32 wave_max_u32(u32 v) {
  v = umax32(v, (u32)__builtin_amdgcn_update_dpp(0, (int)v, 0x111, 0xf, 0xf, false));
  v = umax32(v, (u32)__builtin_amdgcn_update_dpp(0, (int)v, 0x112, 0xf, 0xf, false));
  v = umax32(v, (u32)__builtin_amdgcn_update_dpp(0, (int)v, 0x114, 0xf, 0xf, false));
  v = umax32(v, (u32)__builtin_amdgcn_update_dpp(0, (int)v, 0x118, 0xf, 0xf, false));
  v = umax32(v, (u32)__builtin_amdgcn_update_dpp(0, (int)v, 0x142, 0xa, 0xf, false));
  v = umax32(v, (u32)__builtin_amdgcn_update_dpp(0, (int)v, 0x143, 0xc, 0xf, false));
  return (u32)__builtin_amdgcn_readlane((int)v, 63);
}
// two-phase DPP reduce == lexicographic u64 max over the wave (tie -> min idx)
__device__ inline u64 wave_max_key(u64 lkey) {
  u32 hi = (u32)(lkey >> 32), lo32v = (u32)lkey;
  u32 m = wave_max_u32(hi);
  u32 c = wave_max_u32(hi == m ? lo32v : 0u);
  return ((u64)m << 32) | c;
}

__device__ inline u32 part1by2(u32 x) {   // spread 10 bits -> every 3rd bit
  x &= 0x3ffu;
  x = (x | (x << 16)) & 0x030000FFu;
  x = (x | (x << 8))  & 0x0300F00Fu;
  x = (x | (x << 4))  & 0x030C30C3u;
  x = (x | (x << 2))  & 0x09249249u;
  return x;
}

// ===========================================================================
// Fused kernel (R14 structure). grid = 4 + 8192 blocks x 1024 thr, 64 KB LDS.
// R15 change: fps waves run at s_setprio 3 so co-resident consumer blocks
// (2 blocks/CU) cannot steal issue slots from the latency-critical fps chain;
// consumers stay at priority 0 and fill fps's stall cycles. Consumers also
// pre-stage W1 before spinning on the flag (no dependency, region disjoint).
// Flag protocol: flag[c] = win+1 via relaxed agent-scope atomic (value IS the
// payload). All arithmetic identical to R14 (absmax 0.0).
// ===========================================================================
__global__ __launch_bounds__(1024) void fused_kernel(
    const float* __restrict__ pos, const float* __restrict__ x,
    const float* __restrict__ W1, const float* __restrict__ b1,
    const float* __restrict__ W2, const float* __restrict__ b2,
    const float* __restrict__ W3, const float* __restrict__ b3,
    u32* __restrict__ flag, int* __restrict__ ticket,
    float* __restrict__ out) {
  extern __shared__ u64 smem[];   // 64 KB, multi-purpose
  int t = threadIdx.x;

  // ---- role claim (first-arrival basis; no blockIdx-order assumption) ----
  if (t == 0) *(int*)smem = atomicAdd(ticket, 1);
  __syncthreads();
  int role = *(int*)smem;
  __syncthreads();

  if (role < BCL) {
    // =====================================================================
    // FPS for cloud b = role. R11 body verbatim + flag publication.
    // Priority 3: win issue arbitration over co-resident consumer waves.
    // =====================================================================
    asm volatile("s_setprio 3");
    int b = role, lane = t & 63;
    const float* pb = pos + (size_t)b * NPB * 3;

    for (int i = t; i < NPB; i += 1024) {
      float xx = pb[i * 3], yy = pb[i * 3 + 1], zz = pb[i * 3 + 2];
      u32 xi = (u32)fminf(fmaxf(xx * 1024.0f, 0.0f), 1023.0f);
      u32 yi = (u32)fminf(fmaxf(yy * 1024.0f, 0.0f), 1023.0f);
      u32 zi = (u32)fminf(fmaxf(zz * 1024.0f, 0.0f), 1023.0f);
      u32 m = (part1by2(zi) << 2) | (part1by2(yi) << 1) | part1by2(xi);
      smem[i] = ((u64)m << 13) | (u32)i;
    }
    for (int k = 2; k <= NPB; k <<= 1) {
      for (int j = k >> 1; j > 0; j >>= 1) {
        __syncthreads();
        for (int i = t; i < NPB; i += 1024) {
          int ix = i ^ j;
          if (ix > i) {
            u64 a = smem[i], c = smem[ix];
            bool up = ((i & k) == 0);
            if ((a > c) == up) { smem[i] = c; smem[ix] = a; }
          }
        }
      }
    }
    __syncthreads();
    int oi[8];
    #pragma unroll
    for (int i = 0; i < 8; ++i) oi[i] = (int)(smem[8 * t + i] & 0x1FFFu);
    __syncthreads();

    u64* slot = smem;                // [3] triple-buffered atomicMax slots
    int* s_samp = (int*)(smem + 8);  // 2048 ints

    f32x2 px[4], py[4], pz[4], mind[4];
    u32 lo[8];
    float bxl = 1e30f, bxh = -1e30f, byl = 1e30f, byh = -1e30f, bzl = 1e30f, bzh = -1e30f;
    #pragma unroll
    for (int j = 0; j < 4; ++j) {
      int iA = oi[2 * j], iB = oi[2 * j + 1];
      float xA = pb[iA * 3], yA = pb[iA * 3 + 1], zA = pb[iA * 3 + 2];
      float xB = pb[iB * 3], yB = pb[iB * 3 + 1], zB = pb[iB * 3 + 2];
      px[j] = f32x2{xA, xB}; py[j] = f32x2{yA, yB}; pz[j] = f32x2{zA, zB};
      lo[2 * j] = ~(u32)iA; lo[2 * j + 1] = ~(u32)iB;
      bxl = fminf(bxl, fminf(xA, xB)); bxh = fmaxf(bxh, fmaxf(xA, xB));
      byl = fminf(byl, fminf(yA, yB)); byh = fmaxf(byh, fmaxf(yA, yB));
      bzl = fminf(bzl, fminf(zA, zB)); bzh = fmaxf(bzh, fmaxf(zA, zB));
    }
    u64 lkey = 0, wkey;
    {
      float cx = pb[0], cy = pb[1], cz = pb[2];
      f32x2 mcx = f32x2{-cx, -cx}, mcy = f32x2{-cy, -cy}, mcz = f32x2{-cz, -cz};
      #pragma unroll
      for (int j = 0; j < 4; ++j) {
        f32x2 dx = pk_add(px[j], mcx), dy = pk_add(py[j], mcy), dz = pk_add(pz[j], mcz);
        mind[j] = pk_add(pk_add(pk_mul(dx, dx), pk_mul(dy, dy)), pk_mul(dz, dz));
        u64 kA = ((u64)__float_as_uint(mind[j].x) << 32) | lo[2 * j];
        u64 kB = ((u64)__float_as_uint(mind[j].y) << 32) | lo[2 * j + 1];
        lkey = umax64(lkey, umax64(kA, kB));
      }
      wkey = wave_max_key(lkey);
    }
    if (t < 3) slot[t] = 0;
    if (t == 0) {
      s_samp[0] = 0;
      __hip_atomic_store(&flag[b * MS], 1u, __ATOMIC_RELAXED,
                         __HIP_MEMORY_SCOPE_AGENT);   // center 0: win=0
    }
    __syncthreads();

    int cur = 0, nxt = 1;
    for (int it = 1; it < MS; ++it) {
      if (lane == 0) atomicMax((u64*)&slot[cur], wkey);
      if (t == 0) slot[nxt] = 0;
      __syncthreads();
      u64 g = slot[cur];
      int win = (int)(~(u32)g) & (NPB - 1);
      if (t == 0) {
        s_samp[it] = win;
        __hip_atomic_store(&flag[b * MS + it], (u32)win + 1u, __ATOMIC_RELAXED,
                           __HIP_MEMORY_SCOPE_AGENT);
      }
      float ncx = pb[win * 3], ncy = pb[win * 3 + 1], ncz = pb[win * 3 + 2];
      float lmax = __uint_as_float((u32)(lkey >> 32));
      float ax = fmaxf(fmaxf(__fsub_rn(bxl, ncx), __fsub_rn(ncx, bxh)), 0.0f);
      float ay = fmaxf(fmaxf(__fsub_rn(byl, ncy), __fsub_rn(ncy, byh)), 0.0f);
      float az = fmaxf(fmaxf(__fsub_rn(bzl, ncz), __fsub_rn(ncz, bzh)), 0.0f);
      float lb2 = (ax * ax + ay * ay + az * az) * 0.9999961853f;  // *(1-2^-18)
      bool upd = (lb2 <= lmax);
      if (__ballot(upd)) {
        if (upd) {
          f32x2 mcx = f32x2{-ncx, -ncx}, mcy = f32x2{-ncy, -ncy}, mcz = f32x2{-ncz, -ncz};
          u64 acc = 0;
          #pragma unroll
          for (int j = 0; j < 4; ++j) {
            f32x2 dx = pk_add(px[j], mcx), dy = pk_add(py[j], mcy), dz = pk_add(pz[j], mcz);
            f32x2 d2 = pk_add(pk_add(pk_mul(dx, dx), pk_mul(dy, dy)), pk_mul(dz, dz));
            mind[j].x = fminf(mind[j].x, d2.x);
            mind[j].y = fminf(mind[j].y, d2.y);
            u64 kA = ((u64)__float_as_uint(mind[j].x) << 32) | lo[2 * j];
            u64 kB = ((u64)__float_as_uint(mind[j].y) << 32) | lo[2 * j + 1];
            acc = umax64(acc, umax64(kA, kB));
          }
          lkey = acc;
        }
        wkey = wave_max_key(lkey);
      }
      cur = nxt;
      nxt = nxt + 1 == 3 ? 0 : nxt + 1;
    }
    __syncthreads();
    float* pos_out = out + OFF_POS + (size_t)b * MS * 3;
    float* batch_out = out + OFF_BATCH + (size_t)b * MS;
    for (int m = t; m < MS; m += 1024) {
      int s = s_samp[m];
      pos_out[m * 3] = pb[s * 3];
      pos_out[m * 3 + 1] = pb[s * 3 + 1];
      pos_out[m * 3 + 2] = pb[s * 3 + 2];
      batch_out[m] = (float)b;
    }
    return;
  }

  // =======================================================================
  // Consumer: center c = role - 4 (priority 0). Pre-stage W1, spin on
  // flag[c], then nbr + MLP (R14-proven arithmetic, bit-exact).
  // =======================================================================
  int c = role - BCL;
  int b = c >> 11;
  const float* pb = pos + (size_t)b * NPB * 3;

  // LDS carve (<= 60.9 KB of the 64 KB dynamic buffer)
  u64* cand = smem;                              // 512 u64   (4096 B)
  float* s_feat = (float*)(smem + 512);          // [64][68]  (17408 B)
  float* s_h = s_feat + 64 * 68;                 // [64][68]  (17408 B)
  float* s_w = s_h + 64 * 68;                    // [68][64]  (17408 B)
  float* s_red = s_w + 68 * 64;                  // [16][64]  (4096 B)
  float* s_mask = s_red + 16 * 64;               // 64        (256 B)
  int* s_nbr = (int*)(s_mask + 64);              // 64        (256 B)
  int* s_int = s_nbr + 64;                       // cnt, win

  // ---- pre-stage W1 [67][64] while fps is still producing our flag ----
  for (int idx = t; idx < 67 * 64; idx += 1024)
    s_w[(idx >> 6) * 64 + (idx & 63)] = W1[idx];

  if (t == 0) {
    u32 v;
    while ((v = __hip_atomic_load(&flag[c], __ATOMIC_RELAXED,
                                  __HIP_MEMORY_SCOPE_AGENT)) == 0u)
      __builtin_amdgcn_s_sleep(32);
    s_int[1] = (int)v - 1;        // winner index for this center
    s_int[0] = 0;                 // cnt
  }
  __syncthreads();
  int s = s_int[1] & (NPB - 1);
  float cx = pb[s * 3], cy = pb[s * 3 + 1], cz = pb[s * 3 + 2];

  // ---- radius ball (proven semantics: (d2<<32)|j keys, cap 512) ----
  const float R2CUT = (float)(0.2 * 0.2);   // 0x3D23D70A
  for (int j = t; j < NPB; j += 1024) {
    float dx = __fsub_rn(pb[j * 3], cx);
    float dy = __fsub_rn(pb[j * 3 + 1], cy);
    float dz = __fsub_rn(pb[j * 3 + 2], cz);
    float d2 = __fadd_rn(__fadd_rn(__fmul_rn(dx, dx), __fmul_rn(dy, dy)), __fmul_rn(dz, dz));
    if (d2 <= R2CUT) {
      int sl = atomicAdd(&s_int[0], 1);
      if (sl < 512) cand[sl] = ((u64)__float_as_uint(d2) << 32) | (u32)j;
    }
  }
  __syncthreads();
  int n = s_int[0]; if (n > 512) n = 512;
  for (int i = t; i < 512; i += 1024) if (i >= n) cand[i] = ~0ull;
  __syncthreads();
  for (int k = 2; k <= 512; k <<= 1) {
    for (int j = k >> 1; j > 0; j >>= 1) {
      for (int i = t; i < 512; i += 1024) {
        int ix = i ^ j;
        if (ix > i) {
          u64 a = cand[i], bb = cand[ix];
          bool up = ((i & k) == 0);
          if ((a > bb) == up) { cand[i] = bb; cand[ix] = a; }
        }
      }
      __syncthreads();
    }
  }
  // ---- neighbor list + mask + posdiff ----
  if (t < KN) {
    int j = (t < n) ? (int)(cand[t] & 0xffffffffu) : -1;
    s_nbr[t] = j;
    bool valid = (j >= 0 && j < NPB);
    s_mask[t] = valid ? 0.0f : -__builtin_inff();
    size_t jj = valid ? (size_t)j : (size_t)s;
    for (int d = 0; d < 3; ++d) {
      float pj = pos[((size_t)b * NPB + jj) * 3 + d];
      float pc = pos[((size_t)b * NPB + s) * 3 + d];
      s_feat[t * 68 + 64 + d] = __fsub_rn(pj, pc);
    }
  }
  __syncthreads();
  // ---- gather x: thread (r = t>>4, q = t&15) loads one float4 ----
  {
    int r = t >> 4, q = t & 15;
    int j = s_nbr[r];
    bool valid = (j >= 0 && j < NPB);
    size_t jj = valid ? (size_t)j : 0;
    float4 v = *(const float4*)(x + ((size_t)b * NPB + jj) * 64 + q * 4);
    s_feat[r * 68 + q * 4 + 0] = valid ? v.x : 0.0f;
    s_feat[r * 68 + q * 4 + 1] = valid ? v.y : 0.0f;
    s_feat[r * 68 + q * 4 + 2] = valid ? v.z : 0.0f;
    s_feat[r * 68 + q * 4 + 3] = valid ? v.w : 0.0f;
  }
  __syncthreads();

  // ---- layer 1: thread (r = t>>4, n0 = (t&15)*4), k-sequential (bit-exact) ----
  {
    int r = t >> 4, n0 = (t & 15) * 4;
    float acc[4];
    for (int j = 0; j < 4; ++j) acc[j] = b1[n0 + j];
    for (int k = 0; k < 67; ++k) {
      float f = s_feat[r * 68 + k];
      for (int j = 0; j < 4; ++j) acc[j] += f * s_w[k * 64 + n0 + j];
    }
    __syncthreads();               // all W1/s_feat reads done
    for (int j = 0; j < 4; ++j) s_h[r * 68 + n0 + j] = fmaxf(acc[j], 0.0f);
  }
  // ---- stage W2 [64][64] ----
  for (int idx = t; idx < 64 * 64; idx += 1024)
    s_w[(idx >> 6) * 64 + (idx & 63)] = W2[idx];
  __syncthreads();

  // ---- layer 2 (h2 overwrites s_feat cols 0-63) ----
  {
    int r = t >> 4, n0 = (t & 15) * 4;
    float acc[4];
    for (int j = 0; j < 4; ++j) acc[j] = b2[n0 + j];
    for (int k = 0; k < 64; ++k) {
      float f = s_h[r * 68 + k];
      for (int j = 0; j < 4; ++j) acc[j] += f * s_w[k * 64 + n0 + j];
    }
    __syncthreads();               // all W2/s_h reads done
    for (int j = 0; j < 4; ++j) s_feat[r * 68 + n0 + j] = fmaxf(acc[j], 0.0f);
  }
  __syncthreads();

  // ---- layer 3 in two 64-col halves + fused masked max-pool ----
  for (int h = 0; h < 2; ++h) {
    for (int idx = t; idx < 64 * 64; idx += 1024)
      s_w[(idx >> 6) * 64 + (idx & 63)] = W3[(size_t)(idx >> 6) * 128 + h * 64 + (idx & 63)];
    __syncthreads();
    int nn = t & 63, rg = t >> 6;   // 16 row-groups of 4 rows
    float acc[4];
    float bias = b3[h * 64 + nn];
    for (int rr = 0; rr < 4; ++rr) acc[rr] = bias;
    for (int k = 0; k < 64; ++k) {
      float w = s_w[k * 64 + nn];
      for (int rr = 0; rr < 4; ++rr) acc[rr] += s_feat[(rg * 4 + rr) * 68 + k] * w;
    }
    float m = -__builtin_inff();
    for (int rr = 0; rr < 4; ++rr)
      m = fmaxf(m, fmaxf(acc[rr], 0.0f) + s_mask[rg * 4 + rr]);
    s_red[rg * 64 + nn] = m;
    __syncthreads();
    if (t < 64) {
      float mm = -__builtin_inff();
      for (int g2 = 0; g2 < 16; ++g2) mm = fmaxf(mm, s_red[g2 * 64 + t]);
      out[(size_t)c * 128 + h * 64 + t] = mm;
    }
    __syncthreads();               // protect s_w restage for h=1
  }
}

// ---------------------------------------------------------------------------
extern "C" void kernel_launch(void* const* d_in, const int* in_sizes, int n_in,
                              void* d_out, int out_size, void* d_ws, size_t ws_size,
                              hipStream_t stream) {
  const float* x   = (const float*)d_in[0];
  const float* pos = (const float*)d_in[1];
  // d_in[2] = batch (int32), unused
  const float* W1 = (const float*)d_in[3];
  const float* b1 = (const float*)d_in[4];
  const float* W2 = (const float*)d_in[5];
  const float* b2 = (const float*)d_in[6];
  const float* W3 = (const float*)d_in[7];
  const float* b3 = (const float*)d_in[8];

  float* out = (float*)d_out;
  u32* flag = (u32*)d_ws;               // [8192] 0 = not ready, else win+1
  int* ticket = (int*)d_ws + BCL * MS;  // [1]

  hipMemsetAsync(d_ws, 0, (BCL * MS + 1) * sizeof(u32), stream);
  fused_kernel<<<BCL + BCL * MS, 1024, NPB * sizeof(u64), stream>>>(
      pos, x, W1, b1, W2, b2, W3, b3, flag, ticket, out);
}